// Round 9
// baseline (171.201 us; speedup 1.0000x reference)
//
#include <hip/hip_runtime.h>
#include <stdint.h>

#define KSEL 10
#define NTHREADS 256
#define SPLIT 4
#define CAP 2048            // per-segment candidate slots; LDS ~16.6KB -> 8 blocks/CU
#define BUFSZ (CAP + 16)

typedef unsigned long long ull;

__device__ __forceinline__ ull ullmin(ull a, ull b) { return a < b ? a : b; }

__global__ void __launch_bounds__(NTHREADS, 8)
knn_scan_kernel(const float* __restrict__ ged, const float* __restrict__ y,
                const float* __restrict__ coef, float* __restrict__ out,
                int n_train, ull* __restrict__ part, int* __restrict__ done)
{
    __shared__ ull sbuf[BUFSZ];
    __shared__ int cnt;

    const int tid = threadIdx.x;
    const int bid = blockIdx.x;
    const int row = bid / SPLIT;
    const int seg = bid % SPLIT;

    const float* __restrict__ x = ged + (size_t)row * (size_t)n_train;

    const int h  = (n_train / SPLIT) & ~3;          // 16B-aligned segment size
    const int start = seg * h;
    const int end   = (seg == SPLIT - 1) ? n_train : (seg + 1) * h;
    const int f0 = start >> 2;
    const int f1 = end >> 2;                        // float4 range [f0,f1); tail scalar
    const float4* __restrict__ x4 = (const float4*)x;

    int len = -1;
    float T = 4.0e-3f;                              // ~50 expected survivors per 12.5K segment

    for (int attempt = 0; attempt < 24; ++attempt) {
        if (tid == 0) cnt = 0;
        __syncthreads();

        for (int i = f0 + tid; i < f1; i += NTHREADS) {
            float4 v = x4[i];
            int base = i << 2;
            if (v.x < T) { int p = atomicAdd(&cnt, 1); if (p < CAP) sbuf[p] = ((ull)__float_as_uint(v.x) << 32) | (unsigned)(base    ); }
            if (v.y < T) { int p = atomicAdd(&cnt, 1); if (p < CAP) sbuf[p] = ((ull)__float_as_uint(v.y) << 32) | (unsigned)(base + 1); }
            if (v.z < T) { int p = atomicAdd(&cnt, 1); if (p < CAP) sbuf[p] = ((ull)__float_as_uint(v.z) << 32) | (unsigned)(base + 2); }
            if (v.w < T) { int p = atomicAdd(&cnt, 1); if (p < CAP) sbuf[p] = ((ull)__float_as_uint(v.w) << 32) | (unsigned)(base + 3); }
        }
        for (int i = (f1 << 2) + tid; i < end; i += NTHREADS) {
            float v = x[i];
            if (v < T) { int p = atomicAdd(&cnt, 1); if (p < CAP) sbuf[p] = ((ull)__float_as_uint(v) << 32) | (unsigned)i; }
        }
        __syncthreads();

        int c = cnt;                         // uniform across block
        if (c >= KSEL && c <= CAP) { len = c; break; }
        T = (c < KSEL) ? T * 8.0f : T * 0.125f;
        __syncthreads();                     // protect cnt until everyone has read it
    }

    if (len < 0) {
        // Exact fallback over [start,end): per-thread sorted top-K, two-stage dump
        // (128*KSEL = 1280 <= CAP slots).
        ull loc[KSEL];
        #pragma unroll
        for (int j = 0; j < KSEL; ++j) loc[j] = ~0ull;
        for (int i = start + tid; i < end; i += NTHREADS) {
            ull key = ((ull)__float_as_uint(x[i]) << 32) | (unsigned)i;
            if (key < loc[KSEL - 1]) {
                loc[KSEL - 1] = key;
                #pragma unroll
                for (int j = KSEL - 1; j > 0; --j) {
                    if (loc[j] < loc[j - 1]) { ull t = loc[j]; loc[j] = loc[j - 1]; loc[j - 1] = t; }
                }
            }
        }
        __syncthreads();
        if (tid >= NTHREADS / 2) {
            #pragma unroll
            for (int j = 0; j < KSEL; ++j) sbuf[(tid - NTHREADS / 2) * KSEL + j] = loc[j];
        }
        __syncthreads();
        if (tid < NTHREADS / 2) {
            #pragma unroll
            for (int j = 0; j < KSEL; ++j) {
                ull key = sbuf[tid * KSEL + j];
                if (key < loc[KSEL - 1]) {
                    loc[KSEL - 1] = key;
                    #pragma unroll
                    for (int q = KSEL - 1; q > 0; --q) {
                        if (loc[q] < loc[q - 1]) { ull t = loc[q]; loc[q] = loc[q - 1]; loc[q - 1] = t; }
                    }
                }
            }
        }
        __syncthreads();
        if (tid < NTHREADS / 2) {
            #pragma unroll
            for (int j = 0; j < KSEL; ++j) sbuf[tid * KSEL + j] = loc[j];
        }
        __syncthreads();
        len = (NTHREADS / 2) * KSEL;
    }

    // ---- wave-0-only, barrier-free extraction of this segment's top-10 ----
    if (tid >= 64) return;

    ull mykey = ~0ull;                       // lane r holds segment winner r
    #pragma unroll
    for (int r = 0; r < KSEL; ++r) {
        ull m = ~0ull;
        for (int j = tid; j < len; j += 64) m = ullmin(m, sbuf[j]);
        #pragma unroll
        for (int off = 32; off > 0; off >>= 1)
            m = ullmin(m, (ull)__shfl_xor((long long)m, off, 64));
        if (tid == r) mykey = m;
        for (int j = tid; j < len; j += 64) if (sbuf[j] == m) sbuf[j] = ~0ull;
    }

    // ---- publish partial top-10 at device coherence point ----
    ull* slot = part + ((size_t)row * SPLIT + seg) * KSEL;
    if (tid < KSEL) atomicExch(&slot[tid], mykey);
    __threadfence();
    int last = 0;
    if (tid == 0) last = (atomicAdd(&done[row], 1) == SPLIT - 1);
    last = __shfl(last, 0, 64);
    if (!last) return;
    __threadfence();

    // ---- last finisher merges SPLIT*KSEL partial keys (coherent atomic reads) ----
    ull k = ~0ull;
    if (tid < SPLIT * KSEL) k = atomicAdd(&part[(size_t)row * SPLIT * KSEL + tid], 0ull);

    ull win = ~0ull;                         // lane r holds global winner r
    #pragma unroll
    for (int r = 0; r < KSEL; ++r) {
        ull m = k;
        #pragma unroll
        for (int off = 32; off > 0; off >>= 1)
            m = ullmin(m, (ull)__shfl_xor((long long)m, off, 64));
        if (tid == r) win = m;
        if (k == m) k = ~0ull;               // keys unique (index embedded)
    }

    float s = 0.0f, wy = 0.0f;
    if (tid < KSEL) {
        float cd = coef[0];
        float alpha = cd * cd;
        float v = __uint_as_float((unsigned)(win >> 32));
        int idx = (int)(unsigned)(win & 0xffffffffull);
        s  = expf(-alpha * v);
        wy = s * y[idx];
    }
    #pragma unroll
    for (int off = 32; off > 0; off >>= 1) {
        s  += __shfl_xor(s,  off, 64);
        wy += __shfl_xor(wy, off, 64);
    }
    if (tid == 0) out[row] = wy / s;
}

extern "C" void kernel_launch(void* const* d_in, const int* in_sizes, int n_in,
                              void* d_out, int out_size, void* d_ws, size_t ws_size,
                              hipStream_t stream) {
    const float* ged  = (const float*)d_in[0];
    const float* y    = (const float*)d_in[1];
    const float* coef = (const float*)d_in[2];
    float* out = (float*)d_out;

    const int rows    = out_size;              // = NB_TEST = 1024
    const int n_train = in_sizes[0] / rows;    // = 50000

    int* done = (int*)d_ws;
    size_t done_bytes = (size_t)rows * sizeof(int);
    ull* part = (ull*)((char*)d_ws + ((done_bytes + 255) & ~(size_t)255));

    // reset the row-completion counters every launch (graph-capture-safe)
    hipMemsetAsync(done, 0, done_bytes, stream);
    knn_scan_kernel<<<rows * SPLIT, NTHREADS, 0, stream>>>(ged, y, coef, out,
                                                           n_train, part, done);
}

// Round 10
// 41.078 us; speedup vs baseline: 4.1677x; 4.1677x over previous
//
#include <hip/hip_runtime.h>
#include <stdint.h>

#define KSEL 10
#define NTHREADS 256
#define CAP 2560            // candidate slots; also exactly fits fallback dump 256*10
#define BUFSZ (CAP + 16)

__device__ __forceinline__ unsigned long long ullmin(unsigned long long a, unsigned long long b) {
    return a < b ? a : b;
}

__global__ void __launch_bounds__(NTHREADS)
knn_topk_kernel(const float* __restrict__ ged, const float* __restrict__ y,
                const float* __restrict__ coef, float* __restrict__ out, int n_train)
{
    __shared__ unsigned long long sbuf[BUFSZ];
    __shared__ int cnt;

    const int tid = threadIdx.x;
    const int row = blockIdx.x;
    const float* __restrict__ x = ged + (size_t)row * (size_t)n_train;

    // vector path only if divisible (true here: 50000 % 4 == 0)
    const int n4 = ((n_train & 3) == 0) ? (n_train >> 2) : 0;
    const float4* __restrict__ x4 = (const float4*)x;

    int len = -1;
    float T = 2.0e-3f;

#define PROC(v, base)                                                                                            \
    do {                                                                                                         \
        if ((v).x < T) { int p = atomicAdd(&cnt, 1); if (p < CAP) sbuf[p] = ((unsigned long long)__float_as_uint((v).x) << 32) | (unsigned)((base)    ); } \
        if ((v).y < T) { int p = atomicAdd(&cnt, 1); if (p < CAP) sbuf[p] = ((unsigned long long)__float_as_uint((v).y) << 32) | (unsigned)((base) + 1); } \
        if ((v).z < T) { int p = atomicAdd(&cnt, 1); if (p < CAP) sbuf[p] = ((unsigned long long)__float_as_uint((v).z) << 32) | (unsigned)((base) + 2); } \
        if ((v).w < T) { int p = atomicAdd(&cnt, 1); if (p < CAP) sbuf[p] = ((unsigned long long)__float_as_uint((v).w) << 32) | (unsigned)((base) + 3); } \
    } while (0)

    for (int attempt = 0; attempt < 24; ++attempt) {
        if (tid == 0) cnt = 0;
        __syncthreads();

        for (int i = tid; i < n4; i += NTHREADS) {
            float4 v = x4[i];
            PROC(v, i << 2);
        }
        for (int i = (n4 << 2) + tid; i < n_train; i += NTHREADS) {
            float v = x[i];
            if (v < T) { int p = atomicAdd(&cnt, 1); if (p < CAP) sbuf[p] = ((unsigned long long)__float_as_uint(v) << 32) | (unsigned)i; }
        }
        __syncthreads();

        int c = cnt;                         // uniform across block
        if (c >= KSEL && c <= CAP) { len = c; break; }
        T = (c < KSEL) ? T * 8.0f : T * 0.125f;
        __syncthreads();                     // protect cnt until everyone has read it
    }
#undef PROC

    if (len < 0) {
        // Exact fallback (any data distribution): per-thread sorted top-K, then merge.
        unsigned long long loc[KSEL];
        #pragma unroll
        for (int j = 0; j < KSEL; ++j) loc[j] = ~0ull;
        for (int i = tid; i < n_train; i += NTHREADS) {
            unsigned long long key = ((unsigned long long)__float_as_uint(x[i]) << 32) | (unsigned)i;
            if (key < loc[KSEL - 1]) {
                loc[KSEL - 1] = key;
                #pragma unroll
                for (int j = KSEL - 1; j > 0; --j) {
                    if (loc[j] < loc[j - 1]) {
                        unsigned long long t = loc[j]; loc[j] = loc[j - 1]; loc[j - 1] = t;
                    }
                }
            }
        }
        __syncthreads();
        #pragma unroll
        for (int j = 0; j < KSEL; ++j) sbuf[tid * KSEL + j] = loc[j];
        __syncthreads();
        len = NTHREADS * KSEL;
    }

    // ---- wave-0-only, barrier-free extraction ----
    // Each sbuf slot j is owned by lane (j & 63): removal writes and next-round
    // reads of a slot always happen in the same lane -> no cross-lane hazard.
    if (tid >= 64) return;

    unsigned long long mykey = ~0ull;   // lane r ends up holding winner r (r < KSEL)

    #pragma unroll
    for (int r = 0; r < KSEL; ++r) {
        unsigned long long m = ~0ull;
        for (int j = tid; j < len; j += 64) m = ullmin(m, sbuf[j]);
        #pragma unroll
        for (int off = 32; off > 0; off >>= 1)
            m = ullmin(m, __shfl_xor((long long)m, off, 64));
        // all lanes now hold the round-r winner
        if (tid == r) mykey = m;
        for (int j = tid; j < len; j += 64) if (sbuf[j] == m) sbuf[j] = ~0ull;
    }

    // lanes 0..KSEL-1 gather y and compute exp weights in parallel
    float s = 0.0f, wy = 0.0f;
    if (tid < KSEL) {
        float cd = coef[0];
        float alpha = cd * cd;
        float v = __uint_as_float((unsigned)(mykey >> 32));
        int idx = (int)(unsigned)(mykey & 0xffffffffull);
        s  = expf(-alpha * v);
        wy = s * y[idx];
    }
    #pragma unroll
    for (int off = 32; off > 0; off >>= 1) {
        s  += __shfl_xor(s,  off, 64);
        wy += __shfl_xor(wy, off, 64);
    }
    if (tid == 0) out[row] = wy / s;
}

extern "C" void kernel_launch(void* const* d_in, const int* in_sizes, int n_in,
                              void* d_out, int out_size, void* d_ws, size_t ws_size,
                              hipStream_t stream) {
    const float* ged  = (const float*)d_in[0];
    const float* y    = (const float*)d_in[1];
    const float* coef = (const float*)d_in[2];
    float* out = (float*)d_out;

    const int rows    = out_size;              // = NB_TEST = 1024
    const int n_train = in_sizes[0] / rows;    // = 50000

    knn_topk_kernel<<<rows, NTHREADS, 0, stream>>>(ged, y, coef, out, n_train);
}